// Round 3
// baseline (592.054 us; speedup 1.0000x reference)
//
#include <hip/hip_runtime.h>
#include <math.h>

// ---------------------------------------------------------------------------
// SuperCKAN forward:
//   conv1 (k=5, grid5, n=12)  + pool -> (256,12,12,12)
//   conv2 (k=4, grid10, n=12) + pool -> (256,144,4,4)
//   conv3 (k=3, grid10, n=24) + pool -> (256,3456)
//   fc: x @ (w2@w1)^T + (b1@w2^T + b2) -> (256,10)
// All fp32.
//
// R2: weights staged in LDS, layout [k][j][N] (feature-major, channel-
// contiguous). All weight reads are wave-uniform-address ds_read_b128
// broadcasts -> no L1/sK$ request-port bottleneck (R1 showed the global
// weight path costing ~70us/conv vs a ~7us FMA floor).
// ---------------------------------------------------------------------------

#define B_BATCH 256

// ---- prep: merged weight tables, layout [k][j][N], j=0 base, j=1+g spline --
__global__ __launch_bounds__(256) void prep_weights(
    const float* __restrict__ bw1, const float* __restrict__ sw1, const float* __restrict__ sc1,
    const float* __restrict__ bw2, const float* __restrict__ sw2, const float* __restrict__ sc2,
    const float* __restrict__ bw3, const float* __restrict__ sw3, const float* __restrict__ sc3,
    float* __restrict__ W1m, float* __restrict__ W2m, float* __restrict__ W3m)
{
    int tid = blockIdx.x * 256 + threadIdx.x;
    if (tid < 300) {                     // layer1: n<12, k<25, NF=9, N=12
        int n = tid / 25, k = tid % 25;
        float sc = sc1[n * 25 + k];
        W1m[(k * 9 + 0) * 12 + n] = bw1[n * 25 + k];
        for (int g = 0; g < 8; ++g)
            W1m[(k * 9 + 1 + g) * 12 + n] = sw1[(n * 25 + k) * 8 + g] * sc;
    } else if (tid < 492) {              // layer2: n<12, k<16, NF=14, N=12
        int i = tid - 300;
        int n = i / 16, k = i % 16;
        float sc = sc2[n * 16 + k];
        W2m[(k * 14 + 0) * 12 + n] = bw2[n * 16 + k];
        for (int g = 0; g < 13; ++g)
            W2m[(k * 14 + 1 + g) * 12 + n] = sw2[(n * 16 + k) * 13 + g] * sc;
    } else if (tid < 708) {              // layer3: n<24, k<9, NF=14, N=24
        int i = tid - 492;
        int n = i / 9, k = i % 9;
        float sc = sc3[n * 9 + k];
        W3m[(k * 14 + 0) * 24 + n] = bw3[n * 9 + k];
        for (int g = 0; g < 13; ++g)
            W3m[(k * 14 + 1 + g) * 24 + n] = sw3[(n * 9 + k) * 13 + g] * sc;
    }
}

// ---- prep: folded bias bf = b1 @ w2^T + b2 --------------------------------
__global__ void prep_bf(const float* __restrict__ b1, const float* __restrict__ w2,
                        const float* __restrict__ b2, float* __restrict__ bf)
{
    int lane = threadIdx.x; // 64 threads
    for (int n = 0; n < 10; ++n) {
        float s = 0.f;
        for (int j = lane; j < 256; j += 64) s = fmaf(b1[j], w2[n * 256 + j], s);
        for (int o = 32; o; o >>= 1) s += __shfl_down(s, o, 64);
        if (lane == 0) bf[n] = s + b2[n];
    }
}

// ---- prep: Wf = w2 @ w1  (10 x 3456); grid 135*256 exact ------------------
__global__ __launch_bounds__(256) void wf_kernel(const float* __restrict__ w1,
                                                 const float* __restrict__ w2,
                                                 float* __restrict__ Wf)
{
    int gid = blockIdx.x * 256 + threadIdx.x;
    int n = gid / 3456, m = gid % 3456;
    float s = 0.f;
    for (int j = 0; j < 256; ++j)
        s = fmaf(w2[n * 256 + j], w1[j * 3456 + m], s);
    Wf[n * 3456 + m] = s;
}

// ---- fused KAN conv + 2x2 maxpool -----------------------------------------
// Thread quad (4 lanes, sub = 2x2 conv position) per pooled output position.
// Weights in LDS, layout [K*K][NF][N]; all weight reads are wave-uniform
// float4 broadcasts. Grid is EXACT: no early return.
template <int K, int NINT, int G, int N, int C, int HIN, int WIN, int HP, int WP>
__global__ __launch_bounds__(256) void kan_conv_pool(
    const float* __restrict__ in, const float* __restrict__ W,
    float* __restrict__ out, float g0, float invh)
{
    constexpr int NF = 1 + G;
    constexpr int POS = HP * WP;
    constexpr int WSZ = K * K * NF * N;       // multiple of 4 (N is 12 or 24)
    static_assert((N % 4) == 0, "N multiple of 4");

    __shared__ float sw[WSZ];
    for (int i = threadIdx.x; i < WSZ; i += 256) sw[i] = W[i];
    __syncthreads();

    int tid = blockIdx.x * 256 + threadIdx.x;

    int sub = tid & 3;
    int rem = tid >> 2;
    int pos = rem % POS;
    int bc  = rem / POS;               // b*C + c
    int pi = pos / WP, pj = pos % WP;
    int p = 2 * pi + (sub >> 1);
    int q = 2 * pj + (sub & 1);

    const float* inp = in + bc * (HIN * WIN);

    float acc[N];
#pragma unroll
    for (int n = 0; n < N; ++n) acc[n] = 0.f;

    for (int dy = 0; dy < K; ++dy) {
#pragma unroll
        for (int dx = 0; dx < K; ++dx) {
            float v = inp[(p + dy) * WIN + (q + dx)];

            // features: f[0]=silu(v); f[1..G]=cubic B-spline bases (4-sparse)
            float s  = (v - g0) * invh;
            float sf = floorf(s);
            int   t  = (int)sf;
            float u  = s - sf;
            float u2 = u * u, u3 = u2 * u;
            float um = 1.0f - u;
            float c0 = um * um * um * (1.0f / 6.0f);
            float c1 = (3.0f * u3 - 6.0f * u2 + 4.0f) * (1.0f / 6.0f);
            float c2 = (-3.0f * u3 + 3.0f * u2 + 3.0f * u + 1.0f) * (1.0f / 6.0f);
            float c3 = u3 * (1.0f / 6.0f);
            bool  inr = (t >= 0) && (t < NINT);
            int   i0  = t - 3;

            float f[NF];
            f[0] = v / (1.0f + __expf(-v));
#pragma unroll
            for (int g = 0; g < G; ++g) {
                int m = g - i0;
                float fg = (m == 0) ? c0 : (m == 1) ? c1 : (m == 2) ? c2
                           : (m == 3) ? c3 : 0.0f;
                f[1 + g] = inr ? fg : 0.0f;
            }

            const float* wk = sw + (dy * K + dx) * (NF * N);
#pragma unroll
            for (int j = 0; j < NF; ++j) {
                const float4* wj = (const float4*)(wk + j * N);  // uniform addr
#pragma unroll
                for (int n4 = 0; n4 < N / 4; ++n4) {
                    float4 w4 = wj[n4];                          // ds broadcast
                    acc[n4 * 4 + 0] = fmaf(f[j], w4.x, acc[n4 * 4 + 0]);
                    acc[n4 * 4 + 1] = fmaf(f[j], w4.y, acc[n4 * 4 + 1]);
                    acc[n4 * 4 + 2] = fmaf(f[j], w4.z, acc[n4 * 4 + 2]);
                    acc[n4 * 4 + 3] = fmaf(f[j], w4.w, acc[n4 * 4 + 3]);
                }
            }
        }
    }

    // 2x2 maxpool across the lane quad
#pragma unroll
    for (int n = 0; n < N; ++n) {
        acc[n] = fmaxf(acc[n], __shfl_xor(acc[n], 1, 64));
        acc[n] = fmaxf(acc[n], __shfl_xor(acc[n], 2, 64));
    }

    // each of the 4 lanes writes N/4 channels
    constexpr int NPL = N / 4;
    int n0 = sub * NPL;
    float* op = out + bc * (N * POS) + pos;
#pragma unroll
    for (int i = 0; i < NPL; ++i)
        op[(n0 + i) * POS] = acc[n0 + i];
}

// ---- final GEMV: out = x3 @ Wf^T + bf; grid 2560 waves exact --------------
__global__ __launch_bounds__(256) void fc_kernel(
    const float* __restrict__ x3, const float* __restrict__ Wf,
    const float* __restrict__ bf, float* __restrict__ out)
{
    int wid  = (blockIdx.x * 256 + threadIdx.x) >> 6;
    int lane = threadIdx.x & 63;
    int b = wid / 10, n = wid - b * 10;
    const float* xr = x3 + b * 3456;
    const float* wr = Wf + n * 3456;
    float s = 0.f;
    for (int t = lane; t < 3456; t += 64)
        s = fmaf(xr[t], wr[t], s);
    for (int o = 32; o; o >>= 1) s += __shfl_down(s, o, 64);
    if (lane == 0) out[wid] = s + bf[n];
}

// ---------------------------------------------------------------------------
extern "C" void kernel_launch(void* const* d_in, const int* in_sizes, int n_in,
                              void* d_out, int out_size, void* d_ws, size_t ws_size,
                              hipStream_t stream)
{
    (void)in_sizes; (void)n_in; (void)out_size; (void)ws_size;
    const float* x   = (const float*)d_in[0];
    const float* bw1 = (const float*)d_in[1];
    const float* sw1 = (const float*)d_in[2];
    const float* sc1 = (const float*)d_in[3];
    const float* bw2 = (const float*)d_in[4];
    const float* sw2 = (const float*)d_in[5];
    const float* sc2 = (const float*)d_in[6];
    const float* bw3 = (const float*)d_in[7];
    const float* sw3 = (const float*)d_in[8];
    const float* sc3 = (const float*)d_in[9];
    const float* w1  = (const float*)d_in[10];
    const float* b1  = (const float*)d_in[11];
    const float* w2  = (const float*)d_in[12];
    const float* b2  = (const float*)d_in[13];

    float* ws  = (float*)d_ws;
    float* W1m = ws;              // 25*9*12  = 2700
    float* W2m = ws + 2700;       // 16*14*12 = 2688
    float* W3m = ws + 5388;       // 9*14*24  = 3024
    float* bf  = ws + 8412;       // 10 (+pad)
    float* Wf  = ws + 8448;       // 34560
    float* o1  = ws + 43008;      // 256*12*12*12 = 442368
    float* o2  = ws + 485376;     // 256*144*4*4  = 589824
    float* x3  = ws + 1075200;    // 256*3456     = 884736
    float* out = (float*)d_out;

    prep_weights<<<3, 256, 0, stream>>>(bw1, sw1, sc1, bw2, sw2, sc2,
                                        bw3, sw3, sc3, W1m, W2m, W3m);
    prep_bf<<<1, 64, 0, stream>>>(b1, w2, b2, bf);
    wf_kernel<<<135, 256, 0, stream>>>(w1, w2, Wf);

    const float h1 = 2.0f / 5.0f, h2 = 2.0f / 10.0f;
    // layer1: K=5, NINT=11, G=8, N=12, C=1, 28x28 -> pooled 12x12
    kan_conv_pool<5, 11, 8, 12, 1, 28, 28, 12, 12>
        <<<576, 256, 0, stream>>>(x, W1m, o1, -3.0f * h1 - 1.0f, 1.0f / h1);
    // layer2: K=4, NINT=16, G=13, N=12, C=12, 12x12 -> pooled 4x4
    kan_conv_pool<4, 16, 13, 12, 12, 12, 12, 4, 4>
        <<<768, 256, 0, stream>>>(o1, W2m, o2, -3.0f * h2 - 1.0f, 1.0f / h2);
    // layer3: K=3, NINT=16, G=13, N=24, C=144, 4x4 -> pooled 1x1
    kan_conv_pool<3, 16, 13, 24, 144, 4, 4, 1, 1>
        <<<576, 256, 0, stream>>>(o2, W3m, x3, -3.0f * h2 - 1.0f, 1.0f / h2);

    fc_kernel<<<640, 256, 0, stream>>>(x3, Wf, bf, out);
}

// Round 4
// 100.008 us; speedup vs baseline: 5.9201x; 5.9201x over previous
//
#include <hip/hip_runtime.h>
#include <math.h>

// ---------------------------------------------------------------------------
// SuperCKAN forward:
//   conv1 (k=5, grid5, n=12)  + pool -> (256,12,12,12)
//   conv2 (k=4, grid10, n=12) + pool -> (256,144,4,4)
//   conv3 (k=3, grid10, n=24) + pool -> (256,3456)
//   fc: x @ (w2@w1)^T + (b1@w2^T + b2) -> (256,10)
// All fp32.
//
// R3: sparse-spline conv. Only 4 cubic B-spline bases are nonzero per value;
// read just those 4 weight rows from LDS by per-lane row index (masked at
// boundaries). FMAs per patch element: (1+4)*N instead of (1+G)*N. dy loop
// kept rolled + __launch_bounds__(256,4) to prevent the R2 register blowup
// (R2: VGPR 256 + scratch spills -> 2x regression).
// Weight LDS layout: [K*K][1+G][ROWP], row 0 = base(silu) w, row 1+g = spline.
// ROWP chosen 16B-aligned with good bank spread (12 for N=12, 28 for N=24).
// ---------------------------------------------------------------------------

#define B_BATCH 256

// ---- prep: merged weight tables + folded bias -----------------------------
// blocks 0..2: weight tables; block 3: bf = b1 @ w2^T + b2 (first wave).
__global__ __launch_bounds__(256) void prep_weights(
    const float* __restrict__ bw1, const float* __restrict__ sw1, const float* __restrict__ sc1,
    const float* __restrict__ bw2, const float* __restrict__ sw2, const float* __restrict__ sc2,
    const float* __restrict__ bw3, const float* __restrict__ sw3, const float* __restrict__ sc3,
    const float* __restrict__ b1, const float* __restrict__ w2, const float* __restrict__ b2,
    float* __restrict__ W1m, float* __restrict__ W2m, float* __restrict__ W3m,
    float* __restrict__ bf)
{
    int tid = blockIdx.x * 256 + threadIdx.x;
    if (tid < 300) {                     // layer1: n<12, k<25, NF=9, ROWP=12
        int n = tid / 25, k = tid % 25;
        float sc = sc1[n * 25 + k];
        W1m[(k * 9 + 0) * 12 + n] = bw1[n * 25 + k];
        for (int g = 0; g < 8; ++g)
            W1m[(k * 9 + 1 + g) * 12 + n] = sw1[(n * 25 + k) * 8 + g] * sc;
    } else if (tid < 492) {              // layer2: n<12, k<16, NF=14, ROWP=12
        int i = tid - 300;
        int n = i / 16, k = i % 16;
        float sc = sc2[n * 16 + k];
        W2m[(k * 14 + 0) * 12 + n] = bw2[n * 16 + k];
        for (int g = 0; g < 13; ++g)
            W2m[(k * 14 + 1 + g) * 12 + n] = sw2[(n * 16 + k) * 13 + g] * sc;
    } else if (tid < 708) {              // layer3: n<24, k<9, NF=14, ROWP=28
        int i = tid - 492;
        int n = i / 9, k = i % 9;
        float sc = sc3[n * 9 + k];
        W3m[(k * 14 + 0) * 28 + n] = bw3[n * 9 + k];
        for (int g = 0; g < 13; ++g)
            W3m[(k * 14 + 1 + g) * 28 + n] = sw3[(n * 9 + k) * 13 + g] * sc;
    } else if (tid >= 768 && tid < 832) { // block 3, first wave: bf
        int lane = tid - 768;
        for (int n = 0; n < 10; ++n) {
            float s = 0.f;
            for (int j = lane; j < 256; j += 64) s = fmaf(b1[j], w2[n * 256 + j], s);
            for (int o = 32; o; o >>= 1) s += __shfl_down(s, o, 64);
            if (lane == 0) bf[n] = s + b2[n];
        }
    }
}

// ---- prep: Wf = w2 @ w1  (10 x 3456); grid 135*256 exact ------------------
__global__ __launch_bounds__(256) void wf_kernel(const float* __restrict__ w1,
                                                 const float* __restrict__ w2,
                                                 float* __restrict__ Wf)
{
    int gid = blockIdx.x * 256 + threadIdx.x;
    int n = gid / 3456, m = gid % 3456;
    float s = 0.f;
    for (int j = 0; j < 256; ++j)
        s = fmaf(w2[n * 256 + j], w1[j * 3456 + m], s);
    Wf[n * 3456 + m] = s;
}

// ---- fused KAN conv + 2x2 maxpool, sparse spline --------------------------
// Thread quad (4 lanes, sub = 2x2 conv position) per pooled output position.
// Grid is EXACT (B_BATCH*C*POS*4 threads): no early return.
template <int K, int NINT, int G, int N, int ROWP, int C, int HIN, int WIN,
          int HP, int WP>
__global__ __launch_bounds__(256, 4) void kan_conv_pool(
    const float* __restrict__ in, const float* __restrict__ W,
    float* __restrict__ out, float g0, float invh)
{
    constexpr int NF = 1 + G;
    constexpr int POS = HP * WP;
    constexpr int WSZ = K * K * NF * ROWP;
    static_assert((N % 4) == 0 && (ROWP % 4) == 0, "alignment");

    __shared__ float sw[WSZ];
    for (int i = threadIdx.x; i < WSZ; i += 256) sw[i] = W[i];
    __syncthreads();

    int tid = blockIdx.x * 256 + threadIdx.x;

    int sub = tid & 3;
    int rem = tid >> 2;
    int pos = rem % POS;
    int bc  = rem / POS;               // b*C + c
    int pi = pos / WP, pj = pos % WP;
    int p = 2 * pi + (sub >> 1);
    int q = 2 * pj + (sub & 1);

    const float* inp = in + bc * (HIN * WIN);

    float acc[N];
#pragma unroll
    for (int n = 0; n < N; ++n) acc[n] = 0.f;

#pragma unroll 1
    for (int dy = 0; dy < K; ++dy) {
#pragma unroll
        for (int dx = 0; dx < K; ++dx) {
            float v = inp[(p + dy) * WIN + (q + dx)];

            float s  = (v - g0) * invh;
            float sf = floorf(s);
            int   t  = (int)sf;
            float u  = s - sf;
            float u2 = u * u, u3 = u2 * u;
            float um = 1.0f - u;
            float c[4];
            c[0] = um * um * um * (1.0f / 6.0f);
            c[1] = (3.0f * u3 - 6.0f * u2 + 4.0f) * (1.0f / 6.0f);
            c[2] = (-3.0f * u3 + 3.0f * u2 + 3.0f * u + 1.0f) * (1.0f / 6.0f);
            c[3] = u3 * (1.0f / 6.0f);
            bool inr = (t >= 0) && (t < NINT);
            float sv = v / (1.0f + __expf(-v));      // silu

            const float* wk = sw + (dy * K + dx) * (NF * ROWP);

            // base (silu) row: wave-uniform broadcast reads
#pragma unroll
            for (int n4 = 0; n4 < N / 4; ++n4) {
                float4 w4 = ((const float4*)wk)[n4];
                acc[n4 * 4 + 0] = fmaf(sv, w4.x, acc[n4 * 4 + 0]);
                acc[n4 * 4 + 1] = fmaf(sv, w4.y, acc[n4 * 4 + 1]);
                acc[n4 * 4 + 2] = fmaf(sv, w4.z, acc[n4 * 4 + 2]);
                acc[n4 * 4 + 3] = fmaf(sv, w4.w, acc[n4 * 4 + 3]);
            }

            // 4 active spline bases: per-lane indexed rows, masked at edges
#pragma unroll
            for (int m = 0; m < 4; ++m) {
                int  g   = t - 3 + m;
                bool val = inr && (g >= 0) && (g < G);
                int  gc  = min(max(g, 0), G - 1);
                float cm = val ? c[m] : 0.0f;
                const float4* wr = (const float4*)(wk + (1 + gc) * ROWP);
#pragma unroll
                for (int n4 = 0; n4 < N / 4; ++n4) {
                    float4 w4 = wr[n4];
                    acc[n4 * 4 + 0] = fmaf(cm, w4.x, acc[n4 * 4 + 0]);
                    acc[n4 * 4 + 1] = fmaf(cm, w4.y, acc[n4 * 4 + 1]);
                    acc[n4 * 4 + 2] = fmaf(cm, w4.z, acc[n4 * 4 + 2]);
                    acc[n4 * 4 + 3] = fmaf(cm, w4.w, acc[n4 * 4 + 3]);
                }
            }
        }
    }

    // 2x2 maxpool across the lane quad
#pragma unroll
    for (int n = 0; n < N; ++n) {
        acc[n] = fmaxf(acc[n], __shfl_xor(acc[n], 1, 64));
        acc[n] = fmaxf(acc[n], __shfl_xor(acc[n], 2, 64));
    }

    // each of the 4 lanes writes N/4 channels
    constexpr int NPL = N / 4;
    int n0 = sub * NPL;
    float* op = out + bc * (N * POS) + pos;
#pragma unroll
    for (int i = 0; i < NPL; ++i)
        op[(n0 + i) * POS] = acc[n0 + i];
}

// ---- final GEMV: out = x3 @ Wf^T + bf; grid 2560 waves exact --------------
__global__ __launch_bounds__(256) void fc_kernel(
    const float* __restrict__ x3, const float* __restrict__ Wf,
    const float* __restrict__ bf, float* __restrict__ out)
{
    int wid  = (blockIdx.x * 256 + threadIdx.x) >> 6;
    int lane = threadIdx.x & 63;
    int b = wid / 10, n = wid - b * 10;
    const float* xr = x3 + b * 3456;
    const float* wr = Wf + n * 3456;
    float s = 0.f;
    for (int t = lane; t < 3456; t += 64)
        s = fmaf(xr[t], wr[t], s);
    for (int o = 32; o; o >>= 1) s += __shfl_down(s, o, 64);
    if (lane == 0) out[wid] = s + bf[n];
}

// ---------------------------------------------------------------------------
extern "C" void kernel_launch(void* const* d_in, const int* in_sizes, int n_in,
                              void* d_out, int out_size, void* d_ws, size_t ws_size,
                              hipStream_t stream)
{
    (void)in_sizes; (void)n_in; (void)out_size; (void)ws_size;
    const float* x   = (const float*)d_in[0];
    const float* bw1 = (const float*)d_in[1];
    const float* sw1 = (const float*)d_in[2];
    const float* sc1 = (const float*)d_in[3];
    const float* bw2 = (const float*)d_in[4];
    const float* sw2 = (const float*)d_in[5];
    const float* sc2 = (const float*)d_in[6];
    const float* bw3 = (const float*)d_in[7];
    const float* sw3 = (const float*)d_in[8];
    const float* sc3 = (const float*)d_in[9];
    const float* w1  = (const float*)d_in[10];
    const float* b1  = (const float*)d_in[11];
    const float* w2  = (const float*)d_in[12];
    const float* b2  = (const float*)d_in[13];

    float* ws  = (float*)d_ws;
    float* W1m = ws;              // 25*9*12  = 2700
    float* W2m = ws + 2700;       // 16*14*12 = 2688
    float* W3m = ws + 5388;       // 9*14*28  = 3528
    float* bf  = ws + 8916;       // 10 (+pad)
    float* Wf  = ws + 8960;       // 34560
    float* o1  = ws + 43520;      // 256*12*12*12 = 442368
    float* o2  = ws + 485888;     // 256*144*4*4  = 589824
    float* x3  = ws + 1075712;    // 256*3456     = 884736
    float* out = (float*)d_out;

    prep_weights<<<4, 256, 0, stream>>>(bw1, sw1, sc1, bw2, sw2, sc2,
                                        bw3, sw3, sc3, b1, w2, b2,
                                        W1m, W2m, W3m, bf);
    wf_kernel<<<135, 256, 0, stream>>>(w1, w2, Wf);

    const float h1 = 2.0f / 5.0f, h2 = 2.0f / 10.0f;
    // layer1: K=5, NINT=11, G=8,  N=12, ROWP=12, C=1,   28x28 -> pooled 12x12
    kan_conv_pool<5, 11, 8, 12, 12, 1, 28, 28, 12, 12>
        <<<576, 256, 0, stream>>>(x, W1m, o1, -3.0f * h1 - 1.0f, 1.0f / h1);
    // layer2: K=4, NINT=16, G=13, N=12, ROWP=12, C=12,  12x12 -> pooled 4x4
    kan_conv_pool<4, 16, 13, 12, 12, 12, 12, 12, 4, 4>
        <<<768, 256, 0, stream>>>(o1, W2m, o2, -3.0f * h2 - 1.0f, 1.0f / h2);
    // layer3: K=3, NINT=16, G=13, N=24, ROWP=28, C=144, 4x4  -> pooled 1x1
    kan_conv_pool<3, 16, 13, 24, 28, 144, 4, 4, 1, 1>
        <<<576, 256, 0, stream>>>(o2, W3m, x3, -3.0f * h2 - 1.0f, 1.0f / h2);

    fc_kernel<<<640, 256, 0, stream>>>(x3, Wf, bf, out);
}

// Round 6
// 66.793 us; speedup vs baseline: 8.8640x; 1.4973x over previous
//
#include <hip/hip_runtime.h>
#include <math.h>

// ---------------------------------------------------------------------------
// SuperCKAN forward:
//   conv1 (k=5, grid5, n=12)  + pool -> (256,12,12,12)
//   conv2 (k=4, grid10, n=12) + pool -> (256,144,4,4)
//   conv3 (k=3, grid10, n=24) + pool -> (256,3456)
//   fc: x @ (w2@w1)^T + (b1@w2^T + b2) -> (256,10)
// All fp32.
//
// R5 fix: prep_all block 0 handles 300 weight entries with 256 threads ->
// strided loops (R4 dropped entries 256..299, zeroing most of layer-1
// channels 10-11 -> absmax 9.4e-2). All table-fill roles now use strided
// loops.
// R4 design kept: zero-padded spline tables (rows [base][4 pad][G][4 pad]),
// s clamped to [-1, NINT] so all boundary cases read pad rows (no masking);
// unified prep kernel; float4 fc GEMV.
// ---------------------------------------------------------------------------

#define B_BATCH 256

// Weight layout per layer: [K*K][R][N], R = G+9:
//   row 0: base (silu) w; rows 1..4: zero pad; rows 5..G+4: spline g=0..G-1
//   (scaler folded); rows G+5..G+8: zero pad.
// Spline rows for interval t (clamped to [-1, NINT]) are t+2+m, m=0..3.

// ---- unified prep kernel ---------------------------------------------------
// block 0: W1m   block 1: W2m   block 2: W3m   block 3: bf   blocks 4..138: Wf
__global__ __launch_bounds__(256) void prep_all(
    const float* __restrict__ bw1, const float* __restrict__ sw1, const float* __restrict__ sc1,
    const float* __restrict__ bw2, const float* __restrict__ sw2, const float* __restrict__ sc2,
    const float* __restrict__ bw3, const float* __restrict__ sw3, const float* __restrict__ sc3,
    const float* __restrict__ b1, const float* __restrict__ w2, const float* __restrict__ b2,
    const float* __restrict__ w1,
    float* __restrict__ W1m, float* __restrict__ W2m, float* __restrict__ W3m,
    float* __restrict__ bf, float* __restrict__ Wf)
{
    int blk = blockIdx.x;
    int tid = threadIdx.x;
    if (blk == 0) {                      // layer1: 300 entries, R=17, N=12, G=8
        for (int i = tid; i < 25 * 17 * 12; i += 256) W1m[i] = 0.f;
        __syncthreads();
        for (int e = tid; e < 300; e += 256) {
            int n = e / 25, k = e % 25;
            float sc = sc1[n * 25 + k];
            W1m[(k * 17 + 0) * 12 + n] = bw1[n * 25 + k];
            for (int g = 0; g < 8; ++g)
                W1m[(k * 17 + 5 + g) * 12 + n] = sw1[(n * 25 + k) * 8 + g] * sc;
        }
    } else if (blk == 1) {               // layer2: 192 entries, R=22, N=12, G=13
        for (int i = tid; i < 16 * 22 * 12; i += 256) W2m[i] = 0.f;
        __syncthreads();
        for (int e = tid; e < 192; e += 256) {
            int n = e / 16, k = e % 16;
            float sc = sc2[n * 16 + k];
            W2m[(k * 22 + 0) * 12 + n] = bw2[n * 16 + k];
            for (int g = 0; g < 13; ++g)
                W2m[(k * 22 + 5 + g) * 12 + n] = sw2[(n * 16 + k) * 13 + g] * sc;
        }
    } else if (blk == 2) {               // layer3: 216 entries, R=22, N=24, G=13
        for (int i = tid; i < 9 * 22 * 24; i += 256) W3m[i] = 0.f;
        __syncthreads();
        for (int e = tid; e < 216; e += 256) {
            int n = e / 9, k = e % 9;
            float sc = sc3[n * 9 + k];
            W3m[(k * 22 + 0) * 24 + n] = bw3[n * 9 + k];
            for (int g = 0; g < 13; ++g)
                W3m[(k * 22 + 5 + g) * 24 + n] = sw3[(n * 9 + k) * 13 + g] * sc;
        }
    } else if (blk == 3) {               // folded bias (first wave only)
        if (tid < 64) {
            int lane = tid;
            for (int n = 0; n < 10; ++n) {
                float s = 0.f;
                for (int j = lane; j < 256; j += 64) s = fmaf(b1[j], w2[n * 256 + j], s);
                for (int o = 32; o; o >>= 1) s += __shfl_down(s, o, 64);
                if (lane == 0) bf[n] = s + b2[n];
            }
        }
    } else {                             // Wf = w2 @ w1 (10 x 3456)
        int gid = (blk - 4) * 256 + tid; // 135*256 = 34560 exact
        int n = gid / 3456, m = gid % 3456;
        float s = 0.f;
        for (int j = 0; j < 256; ++j)
            s = fmaf(w2[n * 256 + j], w1[j * 3456 + m], s);
        Wf[n * 3456 + m] = s;
    }
}

// ---- fused KAN conv + 2x2 maxpool, sparse spline, padded tables -----------
// Thread quad (4 lanes, sub = 2x2 conv position) per pooled output position.
// Grid is EXACT (B_BATCH*C*POS*4 threads): no early return.
template <int K, int NINT, int G, int N, int C, int HIN, int WIN, int HP, int WP>
__global__ __launch_bounds__(256, 4) void kan_conv_pool(
    const float* __restrict__ in, const float* __restrict__ W,
    float* __restrict__ out, float g0, float invh)
{
    constexpr int R = G + 9;
    constexpr int POS = HP * WP;
    constexpr int WSZ = K * K * R * N;
    static_assert((N % 4) == 0, "alignment");

    __shared__ float sw[WSZ];
    for (int i = threadIdx.x; i < WSZ; i += 256) sw[i] = W[i];
    __syncthreads();

    int tid = blockIdx.x * 256 + threadIdx.x;

    int sub = tid & 3;
    int rem = tid >> 2;
    int pos = rem % POS;
    int bc  = rem / POS;               // b*C + c
    int pi = pos / WP, pj = pos % WP;
    int p = 2 * pi + (sub >> 1);
    int q = 2 * pj + (sub & 1);

    const float* inp = in + bc * (HIN * WIN);

    float acc[N];
#pragma unroll
    for (int n = 0; n < N; ++n) acc[n] = 0.f;

#pragma unroll 1
    for (int dy = 0; dy < K; ++dy) {
#pragma unroll
        for (int dx = 0; dx < K; ++dx) {
            float v = inp[(p + dy) * WIN + (q + dx)];

            float s  = (v - g0) * invh;
            float sc = fminf(fmaxf(s, -1.0f), (float)NINT);  // sentinels hit pads
            float sf = floorf(sc);
            int   t  = (int)sf;
            float u  = sc - sf;                 // in [0,1]: coeffs stay finite
            float u2 = u * u, u3 = u2 * u;
            float um = 1.0f - u;
            float c0 = um * um * um * (1.0f / 6.0f);
            float c1 = (3.0f * u3 - 6.0f * u2 + 4.0f) * (1.0f / 6.0f);
            float c2 = (-3.0f * u3 + 3.0f * u2 + 3.0f * u + 1.0f) * (1.0f / 6.0f);
            float c3 = u3 * (1.0f / 6.0f);
            float sv = v / (1.0f + __expf(-v)); // silu

            const float* wk = sw + (dy * K + dx) * (R * N);  // base row (uniform)
            const float* wt = wk + (t + 2) * N;              // spline row block

#pragma unroll
            for (int n4 = 0; n4 < N / 4; ++n4) {
                float4 wb = ((const float4*)wk)[n4];
                float4 w0 = ((const float4*)(wt + 0 * N))[n4];
                float4 w1_ = ((const float4*)(wt + 1 * N))[n4];
                float4 w2_ = ((const float4*)(wt + 2 * N))[n4];
                float4 w3_ = ((const float4*)(wt + 3 * N))[n4];
                float a0 = acc[n4 * 4 + 0], a1 = acc[n4 * 4 + 1];
                float a2 = acc[n4 * 4 + 2], a3 = acc[n4 * 4 + 3];
                a0 = fmaf(sv, wb.x, a0); a1 = fmaf(sv, wb.y, a1);
                a2 = fmaf(sv, wb.z, a2); a3 = fmaf(sv, wb.w, a3);
                a0 = fmaf(c0, w0.x, a0); a1 = fmaf(c0, w0.y, a1);
                a2 = fmaf(c0, w0.z, a2); a3 = fmaf(c0, w0.w, a3);
                a0 = fmaf(c1, w1_.x, a0); a1 = fmaf(c1, w1_.y, a1);
                a2 = fmaf(c1, w1_.z, a2); a3 = fmaf(c1, w1_.w, a3);
                a0 = fmaf(c2, w2_.x, a0); a1 = fmaf(c2, w2_.y, a1);
                a2 = fmaf(c2, w2_.z, a2); a3 = fmaf(c2, w2_.w, a3);
                a0 = fmaf(c3, w3_.x, a0); a1 = fmaf(c3, w3_.y, a1);
                a2 = fmaf(c3, w3_.z, a2); a3 = fmaf(c3, w3_.w, a3);
                acc[n4 * 4 + 0] = a0; acc[n4 * 4 + 1] = a1;
                acc[n4 * 4 + 2] = a2; acc[n4 * 4 + 3] = a3;
            }
        }
    }

    // 2x2 maxpool across the lane quad
#pragma unroll
    for (int n = 0; n < N; ++n) {
        acc[n] = fmaxf(acc[n], __shfl_xor(acc[n], 1, 64));
        acc[n] = fmaxf(acc[n], __shfl_xor(acc[n], 2, 64));
    }

    // each of the 4 lanes writes N/4 channels
    constexpr int NPL = N / 4;
    int n0 = sub * NPL;
    float* op = out + bc * (N * POS) + pos;
#pragma unroll
    for (int i = 0; i < NPL; ++i)
        op[(n0 + i) * POS] = acc[n0 + i];
}

// ---- final GEMV: out = x3 @ Wf^T + bf; grid 2560 waves exact --------------
__global__ __launch_bounds__(256) void fc_kernel(
    const float* __restrict__ x3, const float* __restrict__ Wf,
    const float* __restrict__ bf, float* __restrict__ out)
{
    int wid  = (blockIdx.x * 256 + threadIdx.x) >> 6;
    int lane = threadIdx.x & 63;
    int b = wid / 10, n = wid - b * 10;
    const float4* xr = (const float4*)(x3 + b * 3456);
    const float4* wr = (const float4*)(Wf + n * 3456);
    float s = 0.f;
#pragma unroll
    for (int i = 0; i < 13; ++i) {       // 13*64*4 = 3328 floats
        float4 a = xr[lane + i * 64];
        float4 w = wr[lane + i * 64];
        s = fmaf(a.x, w.x, s); s = fmaf(a.y, w.y, s);
        s = fmaf(a.z, w.z, s); s = fmaf(a.w, w.w, s);
    }
    const float* xs = x3 + b * 3456 + 3328;   // remainder 128 floats
    const float* wsp = Wf + n * 3456 + 3328;
    s = fmaf(xs[lane], wsp[lane], s);
    s = fmaf(xs[lane + 64], wsp[lane + 64], s);
    for (int o = 32; o; o >>= 1) s += __shfl_down(s, o, 64);
    if (lane == 0) out[wid] = s + bf[n];
}

// ---------------------------------------------------------------------------
extern "C" void kernel_launch(void* const* d_in, const int* in_sizes, int n_in,
                              void* d_out, int out_size, void* d_ws, size_t ws_size,
                              hipStream_t stream)
{
    (void)in_sizes; (void)n_in; (void)out_size; (void)ws_size;
    const float* x   = (const float*)d_in[0];
    const float* bw1 = (const float*)d_in[1];
    const float* sw1 = (const float*)d_in[2];
    const float* sc1 = (const float*)d_in[3];
    const float* bw2 = (const float*)d_in[4];
    const float* sw2 = (const float*)d_in[5];
    const float* sc2 = (const float*)d_in[6];
    const float* bw3 = (const float*)d_in[7];
    const float* sw3 = (const float*)d_in[8];
    const float* sc3 = (const float*)d_in[9];
    const float* w1  = (const float*)d_in[10];
    const float* b1  = (const float*)d_in[11];
    const float* w2  = (const float*)d_in[12];
    const float* b2  = (const float*)d_in[13];

    float* ws  = (float*)d_ws;
    float* W1m = ws;              // 25*17*12 = 5100
    float* W2m = ws + 5100;       // 16*22*12 = 4224
    float* W3m = ws + 9324;       // 9*22*24  = 4752
    float* bf  = ws + 14080;      // 10 (+pad, 16B aligned)
    float* Wf  = ws + 14144;      // 34560
    float* o1  = ws + 48704;      // 256*12*12*12 = 442368
    float* o2  = ws + 491072;     // 256*144*4*4  = 589824
    float* x3  = ws + 1080896;    // 256*3456     = 884736
    float* out = (float*)d_out;

    prep_all<<<139, 256, 0, stream>>>(bw1, sw1, sc1, bw2, sw2, sc2,
                                      bw3, sw3, sc3, b1, w2, b2, w1,
                                      W1m, W2m, W3m, bf, Wf);

    const float h1 = 2.0f / 5.0f, h2 = 2.0f / 10.0f;
    // layer1: K=5, NINT=11, G=8,  N=12, C=1,   28x28 -> pooled 12x12
    kan_conv_pool<5, 11, 8, 12, 1, 28, 28, 12, 12>
        <<<576, 256, 0, stream>>>(x, W1m, o1, -3.0f * h1 - 1.0f, 1.0f / h1);
    // layer2: K=4, NINT=16, G=13, N=12, C=12,  12x12 -> pooled 4x4
    kan_conv_pool<4, 16, 13, 12, 12, 12, 12, 4, 4>
        <<<768, 256, 0, stream>>>(o1, W2m, o2, -3.0f * h2 - 1.0f, 1.0f / h2);
    // layer3: K=3, NINT=16, G=13, N=24, C=144, 4x4  -> pooled 1x1
    kan_conv_pool<3, 16, 13, 24, 144, 4, 4, 1, 1>
        <<<576, 256, 0, stream>>>(o2, W3m, x3, -3.0f * h2 - 1.0f, 1.0f / h2);

    fc_kernel<<<640, 256, 0, stream>>>(x3, Wf, bf, out);
}